// Round 6
// baseline (583.908 us; speedup 1.0000x reference)
//
#include <hip/hip_runtime.h>

#define NS 131072
#define KC 8
typedef unsigned long long u64;

// ---------------------------------------------------------------------------
// Thread tile: 8 samples (rows st+32m) x 8 outputs (cols ot*8..). 64 accums,
// every register-array index is compile-time static. LDS per K4 step:
// 8 A-reads + 8 B-reads per 256 FMAs = 1.0 B/FMA. B-reads are ot-uniform
// across each st-group -> LDS broadcast. Row stride 20 keeps b128 16B-aligned.
// ---------------------------------------------------------------------------

#define LD4(P) (*reinterpret_cast<const float4*>(&sm[(P)]))
#define LD2(P) (*reinterpret_cast<const float2*>(&sm[(P)]))
#define ST4(P) (*reinterpret_cast<float4*>(&sm[(P)]))
#define ST2(P) (*reinterpret_cast<float2*>(&sm[(P)]))

#define FMA8(ACCR, AV, W0, W1) do { \
  ACCR[0]=fmaf((AV),(W0).x,ACCR[0]); ACCR[1]=fmaf((AV),(W0).y,ACCR[1]); \
  ACCR[2]=fmaf((AV),(W0).z,ACCR[2]); ACCR[3]=fmaf((AV),(W0).w,ACCR[3]); \
  ACCR[4]=fmaf((AV),(W1).x,ACCR[4]); ACCR[5]=fmaf((AV),(W1).y,ACCR[5]); \
  ACCR[6]=fmaf((AV),(W1).z,ACCR[6]); ACCR[7]=fmaf((AV),(W1).w,ACCR[7]); } while(0)

// 4-wide K step: A rows st+32m (col AK*4), B rows BK*4..BK*4+3 (cols JOFF..+7)
#define K4(ACC, ABASE, ASTR, AK, BBASE, BSTR, JOFF, BK) do { \
  const float4 b00=LD4((BBASE)+((BK)*4+0)*(BSTR)+(JOFF)), b01=LD4((BBASE)+((BK)*4+0)*(BSTR)+(JOFF)+4); \
  const float4 b10=LD4((BBASE)+((BK)*4+1)*(BSTR)+(JOFF)), b11=LD4((BBASE)+((BK)*4+1)*(BSTR)+(JOFF)+4); \
  const float4 b20=LD4((BBASE)+((BK)*4+2)*(BSTR)+(JOFF)), b21=LD4((BBASE)+((BK)*4+2)*(BSTR)+(JOFF)+4); \
  const float4 b30=LD4((BBASE)+((BK)*4+3)*(BSTR)+(JOFF)), b31=LD4((BBASE)+((BK)*4+3)*(BSTR)+(JOFF)+4); \
  _Pragma("unroll") \
  for (int m_ = 0; m_ < 8; ++m_) { \
    const float4 av = LD4((ABASE)+(st+32*m_)*(ASTR)+(AK)*4); \
    FMA8(ACC[m_], av.x, b00, b01); FMA8(ACC[m_], av.y, b10, b11); \
    FMA8(ACC[m_], av.z, b20, b21); FMA8(ACC[m_], av.w, b30, b31); } \
} while(0)

#define INIT88(ACC, BPTR, OFF) do { \
  const float4 u_ = *reinterpret_cast<const float4*>(&(BPTR)[(OFF)]); \
  const float4 v_ = *reinterpret_cast<const float4*>(&(BPTR)[(OFF)+4]); \
  _Pragma("unroll") for (int m_ = 0; m_ < 8; ++m_) { \
    ACC[m_][0]=u_.x; ACC[m_][1]=u_.y; ACC[m_][2]=u_.z; ACC[m_][3]=u_.w; \
    ACC[m_][4]=v_.x; ACC[m_][5]=v_.y; ACC[m_][6]=v_.z; ACC[m_][7]=v_.w; } \
} while(0)

#define RELU88(ACC) do { _Pragma("unroll") for (int m_=0;m_<8;++m_) \
  { _Pragma("unroll") for (int j_=0;j_<8;++j_) ACC[m_][j_]=fmaxf(ACC[m_][j_],0.f); } } while(0)

// publish this thread's 8x8 block into the e-slice arena [256][8]
#define PUB_SLICE(ACC, EBASE) do { _Pragma("unroll") for (int m_=0;m_<8;++m_){ \
  const int r_ = st + 32*m_; \
  ST4((EBASE)+r_*8+0) = make_float4(ACC[m_][0],ACC[m_][1],ACC[m_][2],ACC[m_][3]); \
  ST4((EBASE)+r_*8+4) = make_float4(ACC[m_][4],ACC[m_][5],ACC[m_][6],ACC[m_][7]); } } while(0)

// ---------------------------------------------------------------------------
// k_enc arena (words): R0 [0,5120) A-slices(L1) -> W2(L2) -> Wd2(xhat);
// ZD [5120,10240) z then d, stride 20; ES [10240,12288) slices, stride 8;
// WB [12288,13312) W1-chunk -> W3 -> Wd1.  53248 B.
// ---------------------------------------------------------------------------
#define R0 0
#define ZD 5120
#define ES 10240
#define WB 12288
#define SMW 13312

__global__ __launch_bounds__(256, 2) void k_enc(
    const float* __restrict__ x,
    const float* __restrict__ We1, const float* __restrict__ be1,
    const float* __restrict__ We2, const float* __restrict__ be2,
    const float* __restrict__ We3, const float* __restrict__ be3,
    const float* __restrict__ Wd1, const float* __restrict__ bd1,
    const float* __restrict__ Wd2, const float* __restrict__ bd2,
    const float* __restrict__ centers,
    float* __restrict__ out_z, float* __restrict__ out_q,
    float* __restrict__ xhat, float* __restrict__ rec, float* __restrict__ kld,
    int* __restrict__ cidx, int* __restrict__ counts)
{
    __shared__ float sm[SMW];
    const int t  = threadIdx.x;
    const int ot = t & 7, st = t >> 3;
    const int job = ot * 8;
    const int s0 = blockIdx.x * 256;

    // ================= layer 1: K=128 in 8 slices of 16 =================
    float acc1[8][8];
    INIT88(acc1, be1, job);
    #pragma unroll 1
    for (int c = 0; c < 8; ++c) {
        #pragma unroll
        for (int p = 0; p < 4; ++p) {           // x slice, 64B/row coalesced
            const int g = p*256 + t, row = g >> 2, c4 = (g & 3) * 4;
            ST4(R0 + row*20 + c4) = *reinterpret_cast<const float4*>(
                &x[(size_t)(s0+row)*128 + c*16 + c4]);
        }
        {   // We1 rows c*16..+15 -> WB [16][64]
            const int row = t >> 4, c4 = (t & 15) * 4;
            ST4(WB + row*64 + c4) = *reinterpret_cast<const float4*>(
                &We1[(size_t)(c*16 + row)*64 + c4]);
        }
        __syncthreads();
        #pragma unroll
        for (int kcc = 0; kcc < 4; ++kcc) K4(acc1, R0, 20, kcc, WB, 64, job, kcc);
        __syncthreads();
    }
    RELU88(acc1);

    // stage W2 [64][64] -> R0, W3 [64][16] -> WB
    #pragma unroll
    for (int p = 0; p < 4; ++p) {
        const int g = p*256 + t, row = g >> 4, c4 = (g & 15) * 4;
        ST4(R0 + row*64 + c4) = *reinterpret_cast<const float4*>(&We2[(size_t)row*64 + c4]);
    }
    {   const int row = t >> 2, c4 = (t & 3) * 4;
        ST4(WB + row*16 + c4) = *reinterpret_cast<const float4*>(&We3[(size_t)row*16 + c4]); }
    __syncthreads();

    // ================= layer 2: K=64 in 8 e1-slices of 8 =================
    float acc2[8][8];
    INIT88(acc2, be2, job);
    #pragma unroll 1
    for (int p = 0; p < 8; ++p) {
        if (ot == p) PUB_SLICE(acc1, ES);
        __syncthreads();
        K4(acc2, ES, 8, 0, R0, 64, job, 2*p);
        K4(acc2, ES, 8, 1, R0, 64, job, 2*p + 1);
        __syncthreads();
    }
    RELU88(acc2);

    // stage Wd2 [16][128] -> R0 (W2 dead)
    #pragma unroll
    for (int p = 0; p < 2; ++p) {
        const int g = p*256 + t, row = g >> 5, c4 = (g & 31) * 4;
        ST4(R0 + row*128 + c4) = *reinterpret_cast<const float4*>(&Wd2[(size_t)row*128 + c4]);
    }

    // ================= layer 3: K=64 in 8 e2-slices, N=2/thread =================
    float zac[8][2];
    {   const float2 b3 = *reinterpret_cast<const float2*>(&be3[ot*2]);
        #pragma unroll
        for (int m = 0; m < 8; ++m) { zac[m][0] = b3.x; zac[m][1] = b3.y; } }
    #pragma unroll 1
    for (int p = 0; p < 8; ++p) {
        if (ot == p) PUB_SLICE(acc2, ES);
        __syncthreads();
        float2 w0 = LD2(WB + (p*8+0)*16 + ot*2), w1 = LD2(WB + (p*8+1)*16 + ot*2);
        float2 w2 = LD2(WB + (p*8+2)*16 + ot*2), w3 = LD2(WB + (p*8+3)*16 + ot*2);
        float2 w4 = LD2(WB + (p*8+4)*16 + ot*2), w5 = LD2(WB + (p*8+5)*16 + ot*2);
        float2 w6 = LD2(WB + (p*8+6)*16 + ot*2), w7 = LD2(WB + (p*8+7)*16 + ot*2);
        #pragma unroll
        for (int m = 0; m < 8; ++m) {
            const int r = st + 32*m;
            const float4 a0 = LD4(ES + r*8 + 0), a1 = LD4(ES + r*8 + 4);
            float s0a = zac[m][0], s1a = zac[m][1];
            s0a=fmaf(a0.x,w0.x,s0a); s1a=fmaf(a0.x,w0.y,s1a);
            s0a=fmaf(a0.y,w1.x,s0a); s1a=fmaf(a0.y,w1.y,s1a);
            s0a=fmaf(a0.z,w2.x,s0a); s1a=fmaf(a0.z,w2.y,s1a);
            s0a=fmaf(a0.w,w3.x,s0a); s1a=fmaf(a0.w,w3.y,s1a);
            s0a=fmaf(a1.x,w4.x,s0a); s1a=fmaf(a1.x,w4.y,s1a);
            s0a=fmaf(a1.y,w5.x,s0a); s1a=fmaf(a1.y,w5.y,s1a);
            s0a=fmaf(a1.z,w6.x,s0a); s1a=fmaf(a1.z,w6.y,s1a);
            s0a=fmaf(a1.w,w7.x,s0a); s1a=fmaf(a1.w,w7.y,s1a);
            zac[m][0] = s0a; zac[m][1] = s1a;
        }
        __syncthreads();
    }

    // write z -> ZD arena
    #pragma unroll
    for (int m = 0; m < 8; ++m)
        ST2(ZD + (st + 32*m)*20 + ot*2) = make_float2(zac[m][0], zac[m][1]);
    __syncthreads();

    // ======== per-thread row t: z out + student-t/q/argmax + Wd1 stage ========
    {
        const float4 z0 = LD4(ZD + t*20 + 0), z1 = LD4(ZD + t*20 + 4);
        const float4 z2 = LD4(ZD + t*20 + 8), z3 = LD4(ZD + t*20 + 12);
        float4* oz = reinterpret_cast<float4*>(out_z + (size_t)(s0 + t)*16);
        oz[0] = z0; oz[1] = z1; oz[2] = z2; oz[3] = z3;
        const float zz[16] = {z0.x,z0.y,z0.z,z0.w, z1.x,z1.y,z1.z,z1.w,
                              z2.x,z2.y,z2.z,z2.w, z3.x,z3.y,z3.z,z3.w};
        float d2[KC];
        #pragma unroll
        for (int k = 0; k < KC; ++k) {
            float acc = 0.f;
            #pragma unroll
            for (int l = 0; l < 16; ++l) {
                const float dl = zz[l] - centers[k*16 + l];
                acc = fmaf(dl, dl, acc);
            }
            d2[k] = acc;
        }
        float lgt[KC], ex[KC];
        float mm = -1e30f;
        #pragma unroll
        for (int k = 0; k < KC; ++k) { lgt[k] = -log1pf(d2[k]); mm = fmaxf(mm, lgt[k]); }
        float ssum = 0.f;
        #pragma unroll
        for (int k = 0; k < KC; ++k) { ex[k] = expf(lgt[k] - mm); ssum += ex[k]; }
        const float inv = 1.f / ssum;
        float4* oq = reinterpret_cast<float4*>(out_q + (size_t)(s0 + t)*8);
        oq[0] = make_float4(ex[0]*inv, ex[1]*inv, ex[2]*inv, ex[3]*inv);
        oq[1] = make_float4(ex[4]*inv, ex[5]*inv, ex[6]*inv, ex[7]*inv);
        int ci = 0; float best = d2[0];
        #pragma unroll
        for (int k = 1; k < KC; ++k) if (d2[k] < best) { best = d2[k]; ci = k; }
        cidx[s0 + t] = ci;
        #pragma unroll
        for (int k = 0; k < KC; ++k) {
            const u64 mk = __ballot(ci == k);
            if ((t & 63) == 0 && mk) atomicAdd(&counts[k], (int)__popcll(mk));
        }
        kld[s0 + t] = 0.f;
    }
    if (t < 64) ST4(WB + t*4) = *reinterpret_cast<const float4*>(&Wd1[t*4]);
    __syncthreads();

    // ================= decoder: d = relu(z Wd1), N=2/thread =================
    float dac[8][2];
    {   const float2 bb = *reinterpret_cast<const float2*>(&bd1[ot*2]);
        float2 wd[8];
        #pragma unroll
        for (int kk = 0; kk < 8; ++kk) wd[kk] = LD2(WB + kk*16 + ot*2);
        float2 we[8];
        #pragma unroll
        for (int kk = 0; kk < 8; ++kk) we[kk] = LD2(WB + (8+kk)*16 + ot*2);
        #pragma unroll
        for (int m = 0; m < 8; ++m) {
            const int r = st + 32*m;
            const float4 a0 = LD4(ZD + r*20 + 0), a1 = LD4(ZD + r*20 + 4);
            const float4 a2 = LD4(ZD + r*20 + 8), a3 = LD4(ZD + r*20 + 12);
            float s0a = bb.x, s1a = bb.y;
            s0a=fmaf(a0.x,wd[0].x,s0a); s1a=fmaf(a0.x,wd[0].y,s1a);
            s0a=fmaf(a0.y,wd[1].x,s0a); s1a=fmaf(a0.y,wd[1].y,s1a);
            s0a=fmaf(a0.z,wd[2].x,s0a); s1a=fmaf(a0.z,wd[2].y,s1a);
            s0a=fmaf(a0.w,wd[3].x,s0a); s1a=fmaf(a0.w,wd[3].y,s1a);
            s0a=fmaf(a1.x,wd[4].x,s0a); s1a=fmaf(a1.x,wd[4].y,s1a);
            s0a=fmaf(a1.y,wd[5].x,s0a); s1a=fmaf(a1.y,wd[5].y,s1a);
            s0a=fmaf(a1.z,wd[6].x,s0a); s1a=fmaf(a1.z,wd[6].y,s1a);
            s0a=fmaf(a1.w,wd[7].x,s0a); s1a=fmaf(a1.w,wd[7].y,s1a);
            s0a=fmaf(a2.x,we[0].x,s0a); s1a=fmaf(a2.x,we[0].y,s1a);
            s0a=fmaf(a2.y,we[1].x,s0a); s1a=fmaf(a2.y,we[1].y,s1a);
            s0a=fmaf(a2.z,we[2].x,s0a); s1a=fmaf(a2.z,we[2].y,s1a);
            s0a=fmaf(a2.w,we[3].x,s0a); s1a=fmaf(a2.w,we[3].y,s1a);
            s0a=fmaf(a3.x,we[4].x,s0a); s1a=fmaf(a3.x,we[4].y,s1a);
            s0a=fmaf(a3.y,we[5].x,s0a); s1a=fmaf(a3.y,we[5].y,s1a);
            s0a=fmaf(a3.z,we[6].x,s0a); s1a=fmaf(a3.z,we[6].y,s1a);
            s0a=fmaf(a3.w,we[7].x,s0a); s1a=fmaf(a3.w,we[7].y,s1a);
            dac[m][0] = fmaxf(s0a, 0.f); dac[m][1] = fmaxf(s1a, 0.f);
        }
    }
    __syncthreads();                 // all z reads done
    #pragma unroll
    for (int m = 0; m < 8; ++m)
        ST2(ZD + (st + 32*m)*20 + ot*2) = make_float2(dac[m][0], dac[m][1]);
    __syncthreads();

    // ================= xhat: K=16, N=128 in 2 passes + rec =================
    float rp[8] = {0.f,0.f,0.f,0.f,0.f,0.f,0.f,0.f};
    #pragma unroll 1
    for (int h = 0; h < 2; ++h) {
        float accx[8][8];
        INIT88(accx, bd2, h*64 + job);
        #pragma unroll
        for (int kcc = 0; kcc < 4; ++kcc) K4(accx, ZD, 20, kcc, R0, 128, h*64 + job, kcc);
        #pragma unroll
        for (int m = 0; m < 8; ++m) {
            const int r = st + 32*m;
            const float4 xa = *reinterpret_cast<const float4*>(&x[(size_t)(s0+r)*128 + h*64 + job]);
            const float4 xb = *reinterpret_cast<const float4*>(&x[(size_t)(s0+r)*128 + h*64 + job + 4]);
            float df;
            df=accx[m][0]-xa.x; rp[m]=fmaf(df,df,rp[m]);
            df=accx[m][1]-xa.y; rp[m]=fmaf(df,df,rp[m]);
            df=accx[m][2]-xa.z; rp[m]=fmaf(df,df,rp[m]);
            df=accx[m][3]-xa.w; rp[m]=fmaf(df,df,rp[m]);
            df=accx[m][4]-xb.x; rp[m]=fmaf(df,df,rp[m]);
            df=accx[m][5]-xb.y; rp[m]=fmaf(df,df,rp[m]);
            df=accx[m][6]-xb.z; rp[m]=fmaf(df,df,rp[m]);
            df=accx[m][7]-xb.w; rp[m]=fmaf(df,df,rp[m]);
            float4* o = reinterpret_cast<float4*>(&xhat[(size_t)(s0+r)*128 + h*64 + job]);
            o[0] = make_float4(accx[m][0],accx[m][1],accx[m][2],accx[m][3]);
            o[1] = make_float4(accx[m][4],accx[m][5],accx[m][6],accx[m][7]);
        }
    }
    #pragma unroll
    for (int m = 0; m < 8; ++m) sm[ES + (st + 32*m)*8 + ot] = rp[m];
    __syncthreads();
    {   const float4 r0 = LD4(ES + t*8), r1 = LD4(ES + t*8 + 4);
        rec[s0 + t] = (r0.x+r0.y+r0.z+r0.w + r1.x+r1.y+r1.z+r1.w) * (1.f/128.f); }
}

// ---------------------------------------------------------------------------
__global__ void k_scan(const int* __restrict__ counts,
                       int* __restrict__ bases, int* __restrict__ cursors)
{
    if (threadIdx.x == 0) {
        int acc = 0;
        for (int k = 0; k < KC; ++k) { bases[k] = acc; cursors[k] = acc; acc += counts[k]; }
    }
}

__global__ __launch_bounds__(256) void k_scatter(
    const int* __restrict__ cidx, int* __restrict__ cursors, int* __restrict__ seg)
{
    const int s = blockIdx.x * 256 + threadIdx.x;
    const int lane = threadIdx.x & 63;
    const int ci = cidx[s];
    #pragma unroll
    for (int k = 0; k < KC; ++k) {
        const u64 mk = __ballot(ci == k);
        if (ci == k) {
            const int leader = __ffsll(mk) - 1;
            int base = 0;
            if (lane == leader) base = atomicAdd(&cursors[k], (int)__popcll(mk));
            base = __shfl(base, leader, 64);
            seg[base + (int)__popcll(mk & (((u64)1 << lane) - 1))] = s;
        }
    }
}

// ---------------------------------------------------------------------------
// k_heads arena: HA [0,5120) A-slices stride 20; HW2 [5120,9216) Wh2 padded
// [64][64]; HES [9216,11264) stride 8; HWB [11264,12288) Wh1-chunk. 49152 B.
// ---------------------------------------------------------------------------
#define HA  0
#define HW2 5120
#define HES 9216
#define HWB 11264
#define SMH 12288

__global__ __launch_bounds__(256, 2) void k_heads(
    const float* __restrict__ x, const float* __restrict__ zread,
    const float* __restrict__ Wh1, const float* __restrict__ bh1,
    const float* __restrict__ Wh2, const float* __restrict__ bh2,
    const int* __restrict__ counts, const int* __restrict__ bases,
    const int* __restrict__ seg,
    float* __restrict__ surv)
{
    __shared__ float sm[SMH];
    __shared__ int idxs[256];
    const int t  = threadIdx.x;
    const int ot = t & 7, st = t >> 3;
    const int job = ot * 8;

    int k = -1, chunk = 0, pref = 0;
    #pragma unroll
    for (int kk = 0; kk < KC; ++kk) {
        const int ck = (counts[kk] + 255) >> 8;
        if (k < 0) {
            if ((int)blockIdx.x < pref + ck) { k = kk; chunk = (int)blockIdx.x - pref; }
            pref += ck;
        }
    }
    if (k < 0) return;                      // block-uniform, before any barrier
    k     = __builtin_amdgcn_readfirstlane(k);
    chunk = __builtin_amdgcn_readfirstlane(chunk);
    const int cnt  = __builtin_amdgcn_readfirstlane(counts[k]);
    const int base = __builtin_amdgcn_readfirstlane(bases[k]);

    {   const int i = chunk*256 + t;
        idxs[t] = seg[base + ((i < cnt) ? i : (cnt - 1))]; }
    __syncthreads();

    // ================= head L1: K=144 (z 16 + x 128) =================
    float acc1[8][8];
    INIT88(acc1, bh1, (size_t)k*64 + job);
    // z slice
    #pragma unroll
    for (int p = 0; p < 4; ++p) {
        const int g = p*256 + t, row = g >> 2, c4 = (g & 3) * 4;
        ST4(HA + row*20 + c4) = *reinterpret_cast<const float4*>(
            &zread[(size_t)idxs[row]*16 + c4]);
    }
    {   const int row = t >> 4, c4 = (t & 15) * 4;
        ST4(HWB + row*64 + c4) = *reinterpret_cast<const float4*>(
            &Wh1[((size_t)k*144 + row)*64 + c4]); }
    __syncthreads();
    #pragma unroll
    for (int kcc = 0; kcc < 4; ++kcc) K4(acc1, HA, 20, kcc, HWB, 64, job, kcc);
    __syncthreads();
    // x chunks
    #pragma unroll 1
    for (int c = 0; c < 8; ++c) {
        #pragma unroll
        for (int p = 0; p < 4; ++p) {
            const int g = p*256 + t, row = g >> 2, c4 = (g & 3) * 4;
            ST4(HA + row*20 + c4) = *reinterpret_cast<const float4*>(
                &x[(size_t)idxs[row]*128 + c*16 + c4]);
        }
        {   const int row = t >> 4, c4 = (t & 15) * 4;
            ST4(HWB + row*64 + c4) = *reinterpret_cast<const float4*>(
                &Wh1[((size_t)k*144 + 16 + c*16 + row)*64 + c4]); }
        __syncthreads();
        #pragma unroll
        for (int kcc = 0; kcc < 4; ++kcc) K4(acc1, HA, 20, kcc, HWB, 64, job, kcc);
        __syncthreads();
    }
    RELU88(acc1);

    // stage Wh2 [64][50] zero-padded -> HW2 [64][64]
    #pragma unroll 1
    for (int e = t; e < 4096; e += 256) {
        const int row = e >> 6, col = e & 63;
        sm[HW2 + e] = (col < 50) ? Wh2[((size_t)k*64 + row)*50 + col] : 0.f;
    }
    __syncthreads();

    // ================= head L2: K=64 in 8 h1-slices =================
    float acc2[8][8];
    {   float bz[8];
        #pragma unroll
        for (int j = 0; j < 8; ++j) {
            const int col = job + j;
            bz[j] = (col < 50) ? bh2[(size_t)k*50 + col] : 0.f;
        }
        #pragma unroll
        for (int m = 0; m < 8; ++m) {
            #pragma unroll
            for (int j = 0; j < 8; ++j) acc2[m][j] = bz[j];
        } }
    #pragma unroll 1
    for (int p = 0; p < 8; ++p) {
        if (ot == p) PUB_SLICE(acc1, HES);
        __syncthreads();
        K4(acc2, HES, 8, 0, HW2, 64, job, 2*p);
        K4(acc2, HES, 8, 1, HW2, 64, job, 2*p + 1);
        __syncthreads();
    }

    // ================= store surv (cols < 50) =================
    #pragma unroll
    for (int m = 0; m < 8; ++m) {
        const int r = st + 32*m;
        if (chunk*256 + r < cnt) {
            const int idx = idxs[r];
            float* so = &surv[(size_t)idx*50 + job];
            #pragma unroll
            for (int jj = 0; jj < 8; jj += 2)
                if (job + jj < 50)
                    *reinterpret_cast<float2*>(&so[jj]) =
                        make_float2(acc2[m][jj], acc2[m][jj+1]);
        }
    }
}

// ---------------------------------------------------------------------------
extern "C" void kernel_launch(void* const* d_in, const int* in_sizes, int n_in,
                              void* d_out, int out_size, void* d_ws, size_t ws_size,
                              hipStream_t stream)
{
    const float* x   = (const float*)d_in[0];
    const float* We1 = (const float*)d_in[1];
    const float* be1 = (const float*)d_in[2];
    const float* We2 = (const float*)d_in[3];
    const float* be2 = (const float*)d_in[4];
    const float* We3 = (const float*)d_in[5];
    const float* be3 = (const float*)d_in[6];
    const float* Wd1 = (const float*)d_in[7];
    const float* bd1 = (const float*)d_in[8];
    const float* Wd2 = (const float*)d_in[9];
    const float* bd2 = (const float*)d_in[10];
    const float* Wh1 = (const float*)d_in[11];
    const float* bh1 = (const float*)d_in[12];
    const float* Wh2 = (const float*)d_in[13];
    const float* bh2 = (const float*)d_in[14];
    const float* cen = (const float*)d_in[15];
    float* out = (float*)d_out;

    float* out_z  = out;
    float* out_q  = out + (size_t)NS * 16;
    float* out_sv = out + (size_t)NS * 24;
    float* out_xh = out + (size_t)NS * 74;
    float* out_rc = out + (size_t)NS * 202;
    float* out_kl = out + (size_t)NS * 203;

    int* cidx    = (int*)d_ws;       // [NS]
    int* counts  = cidx + NS;        // [8]
    int* bases   = counts + KC;      // [8]
    int* cursors = bases + KC;       // [8]
    int* seg     = cursors + KC;     // [NS]

    hipMemsetAsync(counts, 0, KC * sizeof(int), stream);

    k_enc<<<dim3(NS / 256), dim3(256), 0, stream>>>(
        x, We1, be1, We2, be2, We3, be3, Wd1, bd1, Wd2, bd2, cen,
        out_z, out_q, out_xh, out_rc, out_kl, cidx, counts);

    k_scan<<<dim3(1), dim3(64), 0, stream>>>(counts, bases, cursors);

    k_scatter<<<dim3(NS / 256), dim3(256), 0, stream>>>(cidx, cursors, seg);

    k_heads<<<dim3(NS / 256 + KC), dim3(256), 0, stream>>>(
        x, out_z, Wh1, bh1, Wh2, bh2, counts, bases, seg, out_sv);
}

// Round 8
// 497.347 us; speedup vs baseline: 1.1740x; 1.1740x over previous
//
#include <hip/hip_runtime.h>

#define NS 131072
#define KC 8
typedef unsigned long long u64;

#define LD4(P) (*reinterpret_cast<const float4*>(&sm[(P)]))
#define LD2(P) (*reinterpret_cast<const float2*>(&sm[(P)]))
#define ST4(P) (*reinterpret_cast<float4*>(&sm[(P)]))
#define ST2(P) (*reinterpret_cast<float2*>(&sm[(P)]))

#define FMA8(ACCR, AV, W0, W1) do { \
  ACCR[0]=fmaf((AV),(W0).x,ACCR[0]); ACCR[1]=fmaf((AV),(W0).y,ACCR[1]); \
  ACCR[2]=fmaf((AV),(W0).z,ACCR[2]); ACCR[3]=fmaf((AV),(W0).w,ACCR[3]); \
  ACCR[4]=fmaf((AV),(W1).x,ACCR[4]); ACCR[5]=fmaf((AV),(W1).y,ACCR[5]); \
  ACCR[6]=fmaf((AV),(W1).z,ACCR[6]); ACCR[7]=fmaf((AV),(W1).w,ACCR[7]); } while(0)

// 4-wide K step: A rows st+32m (col AK*4), B rows BK*4.. (cols JOFF..JOFF+7).
// 16 LDS b128 reads per 256 FMAs. All register indices compile-time static.
#define K4(ACC, ABASE, ASTR, AK, BBASE, BSTR, JOFF, BK) do { \
  const float4 b00=LD4((BBASE)+((BK)*4+0)*(BSTR)+(JOFF)), b01=LD4((BBASE)+((BK)*4+0)*(BSTR)+(JOFF)+4); \
  const float4 b10=LD4((BBASE)+((BK)*4+1)*(BSTR)+(JOFF)), b11=LD4((BBASE)+((BK)*4+1)*(BSTR)+(JOFF)+4); \
  const float4 b20=LD4((BBASE)+((BK)*4+2)*(BSTR)+(JOFF)), b21=LD4((BBASE)+((BK)*4+2)*(BSTR)+(JOFF)+4); \
  const float4 b30=LD4((BBASE)+((BK)*4+3)*(BSTR)+(JOFF)), b31=LD4((BBASE)+((BK)*4+3)*(BSTR)+(JOFF)+4); \
  _Pragma("unroll") \
  for (int m_ = 0; m_ < 8; ++m_) { \
    const float4 av = LD4((ABASE)+(st+32*m_)*(ASTR)+(AK)*4); \
    FMA8(ACC[m_], av.x, b00, b01); FMA8(ACC[m_], av.y, b10, b11); \
    FMA8(ACC[m_], av.z, b20, b21); FMA8(ACC[m_], av.w, b30, b31); } \
} while(0)

#define INIT88(ACC, BPTR, OFF) do { \
  const float4 u_ = *reinterpret_cast<const float4*>(&(BPTR)[(OFF)]); \
  const float4 v_ = *reinterpret_cast<const float4*>(&(BPTR)[(OFF)+4]); \
  _Pragma("unroll") for (int m_ = 0; m_ < 8; ++m_) { \
    ACC[m_][0]=u_.x; ACC[m_][1]=u_.y; ACC[m_][2]=u_.z; ACC[m_][3]=u_.w; \
    ACC[m_][4]=v_.x; ACC[m_][5]=v_.y; ACC[m_][6]=v_.z; ACC[m_][7]=v_.w; } \
} while(0)

#define RELU88(ACC) do { _Pragma("unroll") for (int m_=0;m_<8;++m_) \
  { _Pragma("unroll") for (int j_=0;j_<8;++j_) ACC[m_][j_]=fmaxf(ACC[m_][j_],0.f); } } while(0)

// write 8x8 reg tile into arena rows (stride 72), cols job..job+7
#define WRITE_E(ACC) do { _Pragma("unroll") for (int m_=0;m_<8;++m_){ \
  const int r_ = st + 32*m_; \
  ST4(AR + r_*72 + job)     = make_float4(ACC[m_][0],ACC[m_][1],ACC[m_][2],ACC[m_][3]); \
  ST4(AR + r_*72 + job + 4) = make_float4(ACC[m_][4],ACC[m_][5],ACC[m_][6],ACC[m_][7]); } } while(0)

// ---------------------------------------------------------------------------
// k_enc arena layout (words):
// AR  [0,18432)      : staging [256][20] -> e1/e2 [256][72] -> z/d [256][20]
// WB  [18432,19520)  : W1/W2 chunks [16][68] -> W3 [64][16] -> Wd2 halves
// WD1 [19520,19776)  : Wd1 [16][16]
// total 19776 words = 79104 B -> 2 blocks/CU
// ---------------------------------------------------------------------------
#define AR  0
#define WB  18432
#define WD1 19520
#define SMW 19776

__global__ __launch_bounds__(256, 2) void k_enc(
    const float* __restrict__ x,
    const float* __restrict__ We1, const float* __restrict__ be1,
    const float* __restrict__ We2, const float* __restrict__ be2,
    const float* __restrict__ We3, const float* __restrict__ be3,
    const float* __restrict__ Wd1, const float* __restrict__ bd1,
    const float* __restrict__ Wd2, const float* __restrict__ bd2,
    const float* __restrict__ centers,
    float* __restrict__ out_z, float* __restrict__ out_q,
    float* __restrict__ xhat, float* __restrict__ rec, float* __restrict__ kld,
    int* __restrict__ cidx, int* __restrict__ counts)
{
    __shared__ float sm[SMW];
    const int t  = threadIdx.x;
    const int ot = t & 7, st = t >> 3;
    const int job = ot * 8;
    const int s0 = blockIdx.x * 256;

    // ================= L1: K=128, 8 chunks of 16 =================
    {
        float acc1[8][8];
        INIT88(acc1, be1, job);
        #pragma unroll 1
        for (int c = 0; c < 8; ++c) {
            #pragma unroll
            for (int p = 0; p < 4; ++p) {
                const int g = p*256 + t, row = g >> 2, c4 = (g & 3) * 4;
                ST4(AR + row*20 + c4) = *reinterpret_cast<const float4*>(
                    &x[(size_t)(s0+row)*128 + c*16 + c4]);
            }
            {   const int row = t >> 4, c4 = (t & 15) * 4;
                ST4(WB + row*68 + c4) = *reinterpret_cast<const float4*>(
                    &We1[(size_t)(c*16 + row)*64 + c4]); }
            __syncthreads();
            #pragma unroll
            for (int kc = 0; kc < 4; ++kc) K4(acc1, AR, 20, kc, WB, 68, job, kc);
            __syncthreads();
        }
        RELU88(acc1);
        WRITE_E(acc1);            // e1 -> arena stride 72
    }
    __syncthreads();

    // ================= L2: K=64, 4 chunks of 16 =================
    {
        float acc2[8][8];
        INIT88(acc2, be2, job);
        #pragma unroll 1
        for (int c = 0; c < 4; ++c) {
            {   const int row = t >> 4, c4 = (t & 15) * 4;
                ST4(WB + row*68 + c4) = *reinterpret_cast<const float4*>(
                    &We2[(size_t)(c*16 + row)*64 + c4]); }
            __syncthreads();
            #pragma unroll
            for (int kc = 0; kc < 4; ++kc) K4(acc2, AR, 72, c*4 + kc, WB, 68, job, kc);
            __syncthreads();
        }
        RELU88(acc2);
        WRITE_E(acc2);            // e2 -> arena stride 72 (e1 dead)
    }
    // stage W3 [64][16] -> WB ; Wd1 -> WD1
    {   const int row = t >> 2, c4 = (t & 3) * 4;
        ST4(WB + row*16 + c4) = *reinterpret_cast<const float4*>(
            &We3[(size_t)row*16 + c4]); }
    if (t < 64) ST4(WD1 + (t >> 2)*16 + (t & 3)*4) =
        *reinterpret_cast<const float4*>(&Wd1[(t >> 2)*16 + (t & 3)*4]);
    __syncthreads();

    // ================= L3: z, K=64, N=2/thread =================
    float zac[8][2];
    {   const float2 b3 = *reinterpret_cast<const float2*>(&be3[ot*2]);
        #pragma unroll
        for (int m = 0; m < 8; ++m) { zac[m][0] = b3.x; zac[m][1] = b3.y; } }
    #pragma unroll 2
    for (int kc = 0; kc < 16; ++kc) {
        const float2 w0 = LD2(WB + (kc*4+0)*16 + ot*2);
        const float2 w1 = LD2(WB + (kc*4+1)*16 + ot*2);
        const float2 w2 = LD2(WB + (kc*4+2)*16 + ot*2);
        const float2 w3 = LD2(WB + (kc*4+3)*16 + ot*2);
        #pragma unroll
        for (int m = 0; m < 8; ++m) {
            const float4 av = LD4(AR + (st + 32*m)*72 + kc*4);
            float sa = zac[m][0], sb = zac[m][1];
            sa = fmaf(av.x, w0.x, sa); sb = fmaf(av.x, w0.y, sb);
            sa = fmaf(av.y, w1.x, sa); sb = fmaf(av.y, w1.y, sb);
            sa = fmaf(av.z, w2.x, sa); sb = fmaf(av.z, w2.y, sb);
            sa = fmaf(av.w, w3.x, sa); sb = fmaf(av.w, w3.y, sb);
            zac[m][0] = sa; zac[m][1] = sb;
        }
    }
    #pragma unroll
    for (int m = 0; m < 8; ++m)
        *reinterpret_cast<float2*>(&out_z[(size_t)(s0 + st + 32*m)*16 + ot*2]) =
            make_float2(zac[m][0], zac[m][1]);
    __syncthreads();              // all e2 + W3 reads done
    #pragma unroll
    for (int m = 0; m < 8; ++m)
        ST2(AR + (st + 32*m)*20 + ot*2) = make_float2(zac[m][0], zac[m][1]);
    {   // stage Wd2 half0 [16][0..63] -> WB
        const int row = t >> 4, c4 = (t & 15) * 4;
        ST4(WB + row*68 + c4) = *reinterpret_cast<const float4*>(
            &Wd2[(size_t)row*128 + c4]); }
    __syncthreads();

    // ======== per-thread row t: student-t + softmax + argmax + counts ========
    // Direct d2 = sum((z-c)^2) in fp32 — EXACTLY matches reference argmax
    // semantics (Gram expansion flips near-ties; round-7 bug).
    {
        const float4 z0 = LD4(AR + t*20 + 0), z1 = LD4(AR + t*20 + 4);
        const float4 z2 = LD4(AR + t*20 + 8), z3 = LD4(AR + t*20 + 12);
        const float zz[16] = {z0.x,z0.y,z0.z,z0.w, z1.x,z1.y,z1.z,z1.w,
                              z2.x,z2.y,z2.z,z2.w, z3.x,z3.y,z3.z,z3.w};
        float d2[KC];
        #pragma unroll
        for (int k = 0; k < KC; ++k) {
            float acc = 0.f;
            #pragma unroll
            for (int l = 0; l < 16; ++l) {
                const float dl = zz[l] - centers[k*16 + l];
                acc = fmaf(dl, dl, acc);
            }
            d2[k] = acc;
        }
        float lgt[KC], ex[KC];
        float mm = -1e30f;
        #pragma unroll
        for (int k = 0; k < KC; ++k) { lgt[k] = -log1pf(d2[k]); mm = fmaxf(mm, lgt[k]); }
        float ssum = 0.f;
        #pragma unroll
        for (int k = 0; k < KC; ++k) { ex[k] = expf(lgt[k] - mm); ssum += ex[k]; }
        const float inv = 1.f / ssum;
        float4* oq = reinterpret_cast<float4*>(&out_q[(size_t)(s0 + t)*8]);
        oq[0] = make_float4(ex[0]*inv, ex[1]*inv, ex[2]*inv, ex[3]*inv);
        oq[1] = make_float4(ex[4]*inv, ex[5]*inv, ex[6]*inv, ex[7]*inv);
        int ci = 0; float best = d2[0];
        #pragma unroll
        for (int k = 1; k < KC; ++k) if (d2[k] < best) { best = d2[k]; ci = k; }
        cidx[s0 + t] = ci;
        #pragma unroll
        for (int k = 0; k < KC; ++k) {
            const u64 mk = __ballot(ci == k);
            if ((t & 63) == 0 && mk) atomicAdd(&counts[k], (int)__popcll(mk));
        }
        kld[s0 + t] = 0.f;
    }

    // ================= decoder: d = relu(z Wd1 + bd1), N=2/thread =================
    {
        float dac[8][2];
        const float2 bb = *reinterpret_cast<const float2*>(&bd1[ot*2]);
        const float2 u0 = LD2(WD1 + 0*16 + ot*2),  u1 = LD2(WD1 + 1*16 + ot*2);
        const float2 u2 = LD2(WD1 + 2*16 + ot*2),  u3 = LD2(WD1 + 3*16 + ot*2);
        const float2 u4 = LD2(WD1 + 4*16 + ot*2),  u5 = LD2(WD1 + 5*16 + ot*2);
        const float2 u6 = LD2(WD1 + 6*16 + ot*2),  u7 = LD2(WD1 + 7*16 + ot*2);
        const float2 u8 = LD2(WD1 + 8*16 + ot*2),  u9 = LD2(WD1 + 9*16 + ot*2);
        const float2 uA = LD2(WD1 + 10*16 + ot*2), uB = LD2(WD1 + 11*16 + ot*2);
        const float2 uC = LD2(WD1 + 12*16 + ot*2), uD = LD2(WD1 + 13*16 + ot*2);
        const float2 uE = LD2(WD1 + 14*16 + ot*2), uF = LD2(WD1 + 15*16 + ot*2);
        #pragma unroll
        for (int m = 0; m < 8; ++m) {
            const int r = st + 32*m;
            const float4 a0 = LD4(AR + r*20 + 0), a1 = LD4(AR + r*20 + 4);
            const float4 a2 = LD4(AR + r*20 + 8), a3 = LD4(AR + r*20 + 12);
            float sa = bb.x, sb = bb.y;
            sa=fmaf(a0.x,u0.x,sa); sb=fmaf(a0.x,u0.y,sb);
            sa=fmaf(a0.y,u1.x,sa); sb=fmaf(a0.y,u1.y,sb);
            sa=fmaf(a0.z,u2.x,sa); sb=fmaf(a0.z,u2.y,sb);
            sa=fmaf(a0.w,u3.x,sa); sb=fmaf(a0.w,u3.y,sb);
            sa=fmaf(a1.x,u4.x,sa); sb=fmaf(a1.x,u4.y,sb);
            sa=fmaf(a1.y,u5.x,sa); sb=fmaf(a1.y,u5.y,sb);
            sa=fmaf(a1.z,u6.x,sa); sb=fmaf(a1.z,u6.y,sb);
            sa=fmaf(a1.w,u7.x,sa); sb=fmaf(a1.w,u7.y,sb);
            sa=fmaf(a2.x,u8.x,sa); sb=fmaf(a2.x,u8.y,sb);
            sa=fmaf(a2.y,u9.x,sa); sb=fmaf(a2.y,u9.y,sb);
            sa=fmaf(a2.z,uA.x,sa); sb=fmaf(a2.z,uA.y,sb);
            sa=fmaf(a2.w,uB.x,sa); sb=fmaf(a2.w,uB.y,sb);
            sa=fmaf(a3.x,uC.x,sa); sb=fmaf(a3.x,uC.y,sb);
            sa=fmaf(a3.y,uD.x,sa); sb=fmaf(a3.y,uD.y,sb);
            sa=fmaf(a3.z,uE.x,sa); sb=fmaf(a3.z,uE.y,sb);
            sa=fmaf(a3.w,uF.x,sa); sb=fmaf(a3.w,uF.y,sb);
            dac[m][0] = fmaxf(sa, 0.f); dac[m][1] = fmaxf(sb, 0.f);
        }
        __syncthreads();          // all z reads done
        #pragma unroll
        for (int m = 0; m < 8; ++m)
            ST2(AR + (st + 32*m)*20 + ot*2) = make_float2(dac[m][0], dac[m][1]);
    }
    __syncthreads();

    // ================= xhat: K=16, N=128 (2 halves) + rec =================
    float rp[8] = {0.f,0.f,0.f,0.f,0.f,0.f,0.f,0.f};
    {
        float accx[8][8];
        INIT88(accx, bd2, job);
        #pragma unroll
        for (int kc = 0; kc < 4; ++kc) K4(accx, AR, 20, kc, WB, 68, job, kc);
        #pragma unroll
        for (int m = 0; m < 8; ++m) {
            const int r = st + 32*m;
            const float4 xa = *reinterpret_cast<const float4*>(&x[(size_t)(s0+r)*128 + job]);
            const float4 xb = *reinterpret_cast<const float4*>(&x[(size_t)(s0+r)*128 + job + 4]);
            float df;
            df=accx[m][0]-xa.x; rp[m]=fmaf(df,df,rp[m]);
            df=accx[m][1]-xa.y; rp[m]=fmaf(df,df,rp[m]);
            df=accx[m][2]-xa.z; rp[m]=fmaf(df,df,rp[m]);
            df=accx[m][3]-xa.w; rp[m]=fmaf(df,df,rp[m]);
            df=accx[m][4]-xb.x; rp[m]=fmaf(df,df,rp[m]);
            df=accx[m][5]-xb.y; rp[m]=fmaf(df,df,rp[m]);
            df=accx[m][6]-xb.z; rp[m]=fmaf(df,df,rp[m]);
            df=accx[m][7]-xb.w; rp[m]=fmaf(df,df,rp[m]);
            float4* o = reinterpret_cast<float4*>(&xhat[(size_t)(s0+r)*128 + job]);
            o[0] = make_float4(accx[m][0],accx[m][1],accx[m][2],accx[m][3]);
            o[1] = make_float4(accx[m][4],accx[m][5],accx[m][6],accx[m][7]);
        }
    }
    __syncthreads();
    {   const int row = t >> 4, c4 = (t & 15) * 4;
        ST4(WB + row*68 + c4) = *reinterpret_cast<const float4*>(
            &Wd2[(size_t)row*128 + 64 + c4]); }
    __syncthreads();
    {
        float accx[8][8];
        INIT88(accx, bd2, 64 + job);
        #pragma unroll
        for (int kc = 0; kc < 4; ++kc) K4(accx, AR, 20, kc, WB, 68, job, kc);
        #pragma unroll
        for (int m = 0; m < 8; ++m) {
            const int r = st + 32*m;
            const float4 xa = *reinterpret_cast<const float4*>(&x[(size_t)(s0+r)*128 + 64 + job]);
            const float4 xb = *reinterpret_cast<const float4*>(&x[(size_t)(s0+r)*128 + 64 + job + 4]);
            float df;
            df=accx[m][0]-xa.x; rp[m]=fmaf(df,df,rp[m]);
            df=accx[m][1]-xa.y; rp[m]=fmaf(df,df,rp[m]);
            df=accx[m][2]-xa.z; rp[m]=fmaf(df,df,rp[m]);
            df=accx[m][3]-xa.w; rp[m]=fmaf(df,df,rp[m]);
            df=accx[m][4]-xb.x; rp[m]=fmaf(df,df,rp[m]);
            df=accx[m][5]-xb.y; rp[m]=fmaf(df,df,rp[m]);
            df=accx[m][6]-xb.z; rp[m]=fmaf(df,df,rp[m]);
            df=accx[m][7]-xb.w; rp[m]=fmaf(df,df,rp[m]);
            float4* o = reinterpret_cast<float4*>(&xhat[(size_t)(s0+r)*128 + 64 + job]);
            o[0] = make_float4(accx[m][0],accx[m][1],accx[m][2],accx[m][3]);
            o[1] = make_float4(accx[m][4],accx[m][5],accx[m][6],accx[m][7]);
        }
    }
    #pragma unroll
    for (int m = 0; m < 8; ++m) {
        float v = rp[m];
        v += __shfl_xor(v, 1); v += __shfl_xor(v, 2); v += __shfl_xor(v, 4);
        if (ot == 0) rec[s0 + st + 32*m] = v * (1.f/128.f);
    }
}

// ---------------------------------------------------------------------------
__global__ void k_scan(const int* __restrict__ counts,
                       int* __restrict__ bases, int* __restrict__ cursors)
{
    if (threadIdx.x == 0) {
        int acc = 0;
        for (int k = 0; k < KC; ++k) { bases[k] = acc; cursors[k] = acc; acc += counts[k]; }
    }
}

__global__ __launch_bounds__(256) void k_scatter(
    const int* __restrict__ cidx, int* __restrict__ cursors, int* __restrict__ seg)
{
    const int s = blockIdx.x * 256 + threadIdx.x;
    const int lane = threadIdx.x & 63;
    const int ci = cidx[s];
    #pragma unroll
    for (int k = 0; k < KC; ++k) {
        const u64 mk = __ballot(ci == k);
        if (ci == k) {
            const int leader = __ffsll(mk) - 1;
            int base = 0;
            if (lane == leader) base = atomicAdd(&cursors[k], (int)__popcll(mk));
            base = __shfl(base, leader, 64);
            seg[base + (int)__popcll(mk & (((u64)1 << lane) - 1))] = s;
        }
    }
}

// ---------------------------------------------------------------------------
// k_heads: same skeleton. AR [256][72] arena (staging [256][20] overlay),
// WB [16][68] weight chunks. 2 blocks/CU.
// ---------------------------------------------------------------------------
#define SMH 19520

__global__ __launch_bounds__(256, 2) void k_heads(
    const float* __restrict__ x, const float* __restrict__ zread,
    const float* __restrict__ Wh1, const float* __restrict__ bh1,
    const float* __restrict__ Wh2, const float* __restrict__ bh2,
    const int* __restrict__ counts, const int* __restrict__ bases,
    const int* __restrict__ seg,
    float* __restrict__ surv)
{
    __shared__ float sm[SMH];
    __shared__ int idxs[256];
    const int t  = threadIdx.x;
    const int ot = t & 7, st = t >> 3;
    const int job = ot * 8;

    int kk = -1, chunk = 0, pref = 0;
    #pragma unroll
    for (int q = 0; q < KC; ++q) {
        const int ck = (counts[q] + 255) >> 8;
        if (kk < 0) {
            if ((int)blockIdx.x < pref + ck) { kk = q; chunk = (int)blockIdx.x - pref; }
            pref += ck;
        }
    }
    if (kk < 0) return;                     // block-uniform, before any barrier
    kk    = __builtin_amdgcn_readfirstlane(kk);
    chunk = __builtin_amdgcn_readfirstlane(chunk);
    const int cnt  = __builtin_amdgcn_readfirstlane(counts[kk]);
    const int base = __builtin_amdgcn_readfirstlane(bases[kk]);

    {   const int i = chunk*256 + t;
        idxs[t] = seg[base + ((i < cnt) ? i : (cnt - 1))]; }
    __syncthreads();

    // ================= head L1: K=144 (z chunk + 8 x chunks) =================
    {
        float acc1[8][8];
        INIT88(acc1, bh1, (size_t)kk*64 + job);
        // chunk 0: gathered z
        #pragma unroll
        for (int p = 0; p < 4; ++p) {
            const int g = p*256 + t, row = g >> 2, c4 = (g & 3) * 4;
            ST4(AR + row*20 + c4) = *reinterpret_cast<const float4*>(
                &zread[(size_t)idxs[row]*16 + c4]);
        }
        {   const int row = t >> 4, c4 = (t & 15) * 4;
            ST4(WB + row*68 + c4) = *reinterpret_cast<const float4*>(
                &Wh1[((size_t)kk*144 + row)*64 + c4]); }
        __syncthreads();
        #pragma unroll
        for (int kc = 0; kc < 4; ++kc) K4(acc1, AR, 20, kc, WB, 68, job, kc);
        __syncthreads();
        // chunks 1..8: gathered x
        #pragma unroll 1
        for (int c = 0; c < 8; ++c) {
            #pragma unroll
            for (int p = 0; p < 4; ++p) {
                const int g = p*256 + t, row = g >> 2, c4 = (g & 3) * 4;
                ST4(AR + row*20 + c4) = *reinterpret_cast<const float4*>(
                    &x[(size_t)idxs[row]*128 + c*16 + c4]);
            }
            {   const int row = t >> 4, c4 = (t & 15) * 4;
                ST4(WB + row*68 + c4) = *reinterpret_cast<const float4*>(
                    &Wh1[((size_t)kk*144 + 16 + c*16 + row)*64 + c4]); }
            __syncthreads();
            #pragma unroll
            for (int kc = 0; kc < 4; ++kc) K4(acc1, AR, 20, kc, WB, 68, job, kc);
            __syncthreads();
        }
        RELU88(acc1);
        WRITE_E(acc1);            // h1 -> arena stride 72
    }
    __syncthreads();

    // ================= head L2: K=64 in 4 chunks, N=64 (cols>=50 padded) ===
    float acc2[8][8];
    {   float bz[8];
        #pragma unroll
        for (int j = 0; j < 8; ++j) {
            const int col = job + j;
            bz[j] = (col < 50) ? bh2[(size_t)kk*50 + col] : 0.f;
        }
        #pragma unroll
        for (int m = 0; m < 8; ++m) {
            #pragma unroll
            for (int j = 0; j < 8; ++j) acc2[m][j] = bz[j];
        } }
    #pragma unroll 1
    for (int c = 0; c < 4; ++c) {
        {   const int row = t >> 4, c0 = (t & 15) * 4;
            const int gk = c*16 + row;
            float4 v;
            v.x = (c0+0 < 50) ? Wh2[((size_t)kk*64 + gk)*50 + c0+0] : 0.f;
            v.y = (c0+1 < 50) ? Wh2[((size_t)kk*64 + gk)*50 + c0+1] : 0.f;
            v.z = (c0+2 < 50) ? Wh2[((size_t)kk*64 + gk)*50 + c0+2] : 0.f;
            v.w = (c0+3 < 50) ? Wh2[((size_t)kk*64 + gk)*50 + c0+3] : 0.f;
            ST4(WB + row*68 + c0) = v; }
        __syncthreads();
        #pragma unroll
        for (int kc = 0; kc < 4; ++kc) K4(acc2, AR, 72, c*4 + kc, WB, 68, job, kc);
        __syncthreads();
    }

    // ================= store surv (cols < 50, rows < cnt) =================
    #pragma unroll
    for (int m = 0; m < 8; ++m) {
        const int r = st + 32*m;
        if (chunk*256 + r < cnt) {
            float* so = &surv[(size_t)idxs[r]*50 + job];   // 8B-aligned (200B rows)
            if (ot < 6) {
                *reinterpret_cast<float2*>(&so[0]) = make_float2(acc2[m][0], acc2[m][1]);
                *reinterpret_cast<float2*>(&so[2]) = make_float2(acc2[m][2], acc2[m][3]);
                *reinterpret_cast<float2*>(&so[4]) = make_float2(acc2[m][4], acc2[m][5]);
                *reinterpret_cast<float2*>(&so[6]) = make_float2(acc2[m][6], acc2[m][7]);
            } else if (ot == 6) {
                *reinterpret_cast<float2*>(&so[0]) = make_float2(acc2[m][0], acc2[m][1]);
            }
        }
    }
}

// ---------------------------------------------------------------------------
extern "C" void kernel_launch(void* const* d_in, const int* in_sizes, int n_in,
                              void* d_out, int out_size, void* d_ws, size_t ws_size,
                              hipStream_t stream)
{
    const float* x   = (const float*)d_in[0];
    const float* We1 = (const float*)d_in[1];
    const float* be1 = (const float*)d_in[2];
    const float* We2 = (const float*)d_in[3];
    const float* be2 = (const float*)d_in[4];
    const float* We3 = (const float*)d_in[5];
    const float* be3 = (const float*)d_in[6];
    const float* Wd1 = (const float*)d_in[7];
    const float* bd1 = (const float*)d_in[8];
    const float* Wd2 = (const float*)d_in[9];
    const float* bd2 = (const float*)d_in[10];
    const float* Wh1 = (const float*)d_in[11];
    const float* bh1 = (const float*)d_in[12];
    const float* Wh2 = (const float*)d_in[13];
    const float* bh2 = (const float*)d_in[14];
    const float* cen = (const float*)d_in[15];
    float* out = (float*)d_out;

    float* out_z  = out;
    float* out_q  = out + (size_t)NS * 16;
    float* out_sv = out + (size_t)NS * 24;
    float* out_xh = out + (size_t)NS * 74;
    float* out_rc = out + (size_t)NS * 202;
    float* out_kl = out + (size_t)NS * 203;

    int* cidx    = (int*)d_ws;       // [NS]
    int* counts  = cidx + NS;        // [8]
    int* bases   = counts + KC;      // [8]
    int* cursors = bases + KC;       // [8]
    int* seg     = cursors + KC;     // [NS]

    hipMemsetAsync(counts, 0, KC * sizeof(int), stream);

    k_enc<<<dim3(NS / 256), dim3(256), 0, stream>>>(
        x, We1, be1, We2, be2, We3, be3, Wd1, bd1, Wd2, bd2, cen,
        out_z, out_q, out_xh, out_rc, out_kl, cidx, counts);

    k_scan<<<dim3(1), dim3(64), 0, stream>>>(counts, bases, cursors);

    k_scatter<<<dim3(NS / 256), dim3(256), 0, stream>>>(cidx, cursors, seg);

    k_heads<<<dim3(NS / 256 + KC), dim3(256), 0, stream>>>(
        x, out_z, Wh1, bh1, Wh2, bh2, counts, bases, seg, out_sv);
}